// Round 2
// baseline (15321.274 us; speedup 1.0000x reference)
//
#include <hip/hip_runtime.h>
#include <hip/hip_bf16.h>

// ---------------------------------------------------------------------------
// C4 equivariant CNN, fp32 direct-conv baseline.
// Pipeline: lift/group filter transforms -> conv0 .. conv5 (pool fused into
// conv1/conv3) -> global mean -> fc1(relu) -> fc2.
// Round 2 fix: slot A was 12,988,672 floats but conv0 output needs
// 13,000,704 (64*24*92*92) -> tail overflowed into slot B and was racily
// overwritten by conv1. Offsets corrected.
// ---------------------------------------------------------------------------

// dest[y][x] = src[sy][sx] for rot90^r (counterclockwise, numpy convention)
__device__ __forceinline__ void rot_src(int r, int K, int y, int x, int& sy, int& sx) {
    switch (r & 3) {
        case 0: sy = y;         sx = x;         break;
        case 1: sy = x;         sx = K - 1 - y; break;
        case 2: sy = K - 1 - y; sx = K - 1 - x; break;
        default: sy = K - 1 - x; sx = y;        break;
    }
}

// w0: (6,1,7,7) -> F0: (24,1,7,7);  F0[o*4+r] = rot_r(w0[o])
__global__ void lift_w0_kernel(const float* __restrict__ w, float* __restrict__ f) {
    const int K = 7, KK = 49;
    int idx = blockIdx.x * blockDim.x + threadIdx.x;
    if (idx >= 24 * KK) return;
    int kk = idx % KK, c = idx / KK;
    int y = kk / K, x = kk % K;
    int r = c & 3, o = c >> 2;
    int sy, sx;
    rot_src(r, K, y, x, sy, sx);
    f[idx] = w[o * KK + sy * K + sx];
}

// w: (O,I,4,5,5) -> F: (O*4, I*4, 5,5); F[o*4+r][i*4+s] = rot_r(w[o][i][(s-r)%4])
__global__ void group_w_kernel(const float* __restrict__ w, float* __restrict__ f,
                               int O, int I) {
    const int K = 5, KK = 25;
    int idx = blockIdx.x * blockDim.x + threadIdx.x;
    int total = O * 4 * I * 4 * KK;
    if (idx >= total) return;
    int kk = idx % KK; int c = idx / KK;
    int y = kk / K, x = kk % K;
    int icg = c % (I * 4); int oc = c / (I * 4);
    int s = icg & 3, i = icg >> 2;
    int r = oc & 3, o = oc >> 2;
    int g = (s - r + 4) & 3;
    int sy, sx;
    rot_src(r, K, y, x, sy, sx);
    f[idx] = w[(((o * I + i) * 4 + g) * KK) + sy * K + sx];
}

// Direct conv (cross-correlation), bias per group (bias[oc>>2]), ReLU.
// POOL=false: each thread -> 4 consecutive x outputs at one (n,oc,oy).
// POOL=true : each thread -> 4 consecutive POOLED x outputs at one (n,oc,py);
//             computes the 2x8 conv patch and maxes 2x2 windows.
template <int K, bool POOL>
__global__ __launch_bounds__(256) void conv_kernel(
        const float* __restrict__ in, const float* __restrict__ wf,
        const float* __restrict__ bias, float* __restrict__ out,
        int N, int IC, int H, int W,
        int OC, int OH, int OW, int pad, int OWq) {
    int idx = blockIdx.x * blockDim.x + threadIdx.x;
    int total = N * OC * OH * OWq;
    if (idx >= total) return;
    int xq = idx % OWq; int t = idx / OWq;
    int oy = t % OH; t /= OH;
    int oc = t % OC; int n = t / OC;
    float bv = bias[oc >> 2];

    if (!POOL) {
        int ox0 = xq * 4;
        float acc[4] = {0.f, 0.f, 0.f, 0.f};
        for (int ic = 0; ic < IC; ++ic) {
            const float* ip = in + (size_t)((n * IC + ic) * H) * W;
            const float* wp = wf + (size_t)(oc * IC + ic) * (K * K);
#pragma unroll
            for (int ky = 0; ky < K; ++ky) {
                int iy = oy + ky - pad;
                if (iy < 0 || iy >= H) continue;
                const float* row = ip + (size_t)iy * W;
                float xv[K + 3];
#pragma unroll
                for (int tt = 0; tt < K + 3; ++tt) {
                    int ix = ox0 - pad + tt;
                    xv[tt] = (ix >= 0 && ix < W) ? row[ix] : 0.f;
                }
#pragma unroll
                for (int kx = 0; kx < K; ++kx) {
                    float wv = wp[ky * K + kx];
                    acc[0] = fmaf(wv, xv[kx], acc[0]);
                    acc[1] = fmaf(wv, xv[kx + 1], acc[1]);
                    acc[2] = fmaf(wv, xv[kx + 2], acc[2]);
                    acc[3] = fmaf(wv, xv[kx + 3], acc[3]);
                }
            }
        }
        size_t ob = (size_t)((n * OC + oc) * OH + oy) * OW + xq * 4;
#pragma unroll
        for (int j = 0; j < 4; ++j) {
            int ox = xq * 4 + j;
            if (ox < OW) out[ob + j] = fmaxf(acc[j] + bv, 0.f);
        }
    } else {
        int px0 = xq * 4;       // pooled x start
        int ox0 = px0 * 2;      // conv x start (8 wide)
        float acc[2][8];
#pragma unroll
        for (int d = 0; d < 2; ++d)
#pragma unroll
            for (int j = 0; j < 8; ++j) acc[d][j] = 0.f;

        for (int ic = 0; ic < IC; ++ic) {
            const float* ip = in + (size_t)((n * IC + ic) * H) * W;
            const float* wp = wf + (size_t)(oc * IC + ic) * (K * K);
#pragma unroll
            for (int ky = 0; ky < K; ++ky) {
                float wrow[K];
#pragma unroll
                for (int kx = 0; kx < K; ++kx) wrow[kx] = wp[ky * K + kx];
#pragma unroll
                for (int dy = 0; dy < 2; ++dy) {
                    int iy = 2 * oy + dy + ky - pad;
                    if (iy < 0 || iy >= H) continue;
                    const float* row = ip + (size_t)iy * W;
                    float xv[K + 7];
#pragma unroll
                    for (int tt = 0; tt < K + 7; ++tt) {
                        int ix = ox0 - pad + tt;
                        xv[tt] = (ix >= 0 && ix < W) ? row[ix] : 0.f;
                    }
#pragma unroll
                    for (int kx = 0; kx < K; ++kx) {
                        float wv = wrow[kx];
#pragma unroll
                        for (int j = 0; j < 8; ++j)
                            acc[dy][j] = fmaf(wv, xv[kx + j], acc[dy][j]);
                    }
                }
            }
        }
        size_t ob = (size_t)((n * OC + oc) * OH + oy) * OW + px0;
#pragma unroll
        for (int j = 0; j < 4; ++j) {
            int px = px0 + j;
            if (px < OW) {
                float m = fmaxf(fmaxf(acc[0][2 * j], acc[0][2 * j + 1]),
                                fmaxf(acc[1][2 * j], acc[1][2 * j + 1]));
                out[ob + j] = fmaxf(m + bv, 0.f);
            }
        }
    }
}

// one wave per (n,c) channel: mean over HW
__global__ void mean_kernel(const float* __restrict__ in, float* __restrict__ out,
                            int NC, int HW, float inv) {
    int gid = blockIdx.x * blockDim.x + threadIdx.x;
    int wid = gid >> 6;
    int lane = threadIdx.x & 63;
    if (wid >= NC) return;
    const float* p = in + (size_t)wid * HW;
    float s = 0.f;
    for (int t = lane; t < HW; t += 64) s += p[t];
#pragma unroll
    for (int off = 32; off > 0; off >>= 1) s += __shfl_down(s, off, 64);
    if (lane == 0) out[wid] = s * inv;
}

// single block: fc1 (64x64, relu) then fc2 (10x64)
__global__ void fc_kernel(const float* __restrict__ mean, const float* __restrict__ fw1,
                          const float* __restrict__ fb1, const float* __restrict__ fw2,
                          const float* __restrict__ fb2, float* __restrict__ out) {
    __shared__ float m[4096];
    __shared__ float h1[4096];
    int tid = threadIdx.x;
    for (int i = tid; i < 4096; i += 256) m[i] = mean[i];
    __syncthreads();
    for (int i = tid; i < 4096; i += 256) {
        int n = i >> 6, j = i & 63;
        float s = fb1[j];
        for (int k = 0; k < 64; ++k) s = fmaf(m[n * 64 + k], fw1[j * 64 + k], s);
        h1[i] = fmaxf(s, 0.f);
    }
    __syncthreads();
    for (int i = tid; i < 640; i += 256) {
        int n = i / 10, j2 = i % 10;
        float s = fb2[j2];
        for (int j = 0; j < 64; ++j) s = fmaf(h1[n * 64 + j], fw2[j2 * 64 + j], s);
        out[i] = s;
    }
}

extern "C" void kernel_launch(void* const* d_in, const int* in_sizes, int n_in,
                              void* d_out, int out_size, void* d_ws, size_t ws_size,
                              hipStream_t stream) {
    const float* x   = (const float*)d_in[0];
    const float* w0  = (const float*)d_in[1];
    const float* b0  = (const float*)d_in[2];
    const float* w1  = (const float*)d_in[3];
    const float* b1  = (const float*)d_in[4];
    const float* w2  = (const float*)d_in[5];
    const float* b2  = (const float*)d_in[6];
    const float* w3  = (const float*)d_in[7];
    const float* b3  = (const float*)d_in[8];
    const float* w4  = (const float*)d_in[9];
    const float* b4  = (const float*)d_in[10];
    const float* w5  = (const float*)d_in[11];
    const float* b5  = (const float*)d_in[12];
    const float* fw1 = (const float*)d_in[13];
    const float* fb1 = (const float*)d_in[14];
    const float* fw2 = (const float*)d_in[15];
    const float* fb2 = (const float*)d_in[16];

    float* ws = (float*)d_ws;
    // filter buffers (floats): F0 1176, F1 28800, F2 57600, F3 115200,
    // F4 230400, F5 153600
    float* F0 = ws + 0;
    float* F1 = ws + 1280;
    float* F2 = ws + 30080;
    float* F3 = ws + 87680;
    float* F4 = ws + 202880;
    float* F5 = ws + 433280;
    float* MEANB = ws + 586880;                // 4096 -> ends 590976
    // slot A: needs max(13000704 [conv0], 6500352 [conv2], 3250176 [conv4])
    float* A = ws + 591104;                    // ends 13,591,808
    // slot B: needs max(6500352 [conv1], 3250176 [conv3], 1806336 [conv5])
    float* B = ws + 13592064;                  // ends 20,092,416 (~76.6 MiB)

    // --- filter transforms ---
    hipLaunchKernelGGL(lift_w0_kernel, dim3((24 * 49 + 255) / 256), dim3(256), 0, stream, w0, F0);
    auto gw = [&](const float* w, float* f, int O, int I) {
        int total = O * 4 * I * 4 * 25;
        hipLaunchKernelGGL(group_w_kernel, dim3((total + 255) / 256), dim3(256), 0, stream, w, f, O, I);
    };
    gw(w1, F1, 12, 6);
    gw(w2, F2, 12, 12);
    gw(w3, F3, 24, 12);
    gw(w4, F4, 24, 24);
    gw(w5, F5, 16, 24);

    const int N = 64;

    // conv0: (64,1,96,96) -> (64,24,92,92), K=7, pad=1
    {
        int IC = 1, H = 96, W = 96, OC = 24, OH = 92, OW = 92, pad = 1;
        int OWq = (OW + 3) / 4;
        int total = N * OC * OH * OWq;
        hipLaunchKernelGGL((conv_kernel<7, false>), dim3((total + 255) / 256), dim3(256), 0, stream,
                           x, F0, b0, A, N, IC, H, W, OC, OH, OW, pad, OWq);
    }
    // conv1 + pool: (64,24,92,92) -> (64,48,46,46), K=5, pad=2
    {
        int IC = 24, H = 92, W = 92, OC = 48, OH = 46, OW = 46, pad = 2;
        int OWq = (OW + 3) / 4;
        int total = N * OC * OH * OWq;
        hipLaunchKernelGGL((conv_kernel<5, true>), dim3((total + 255) / 256), dim3(256), 0, stream,
                           A, F1, b1, B, N, IC, H, W, OC, OH, OW, pad, OWq);
    }
    // conv2: (64,48,46,46) -> (64,48,46,46), K=5, pad=2
    {
        int IC = 48, H = 46, W = 46, OC = 48, OH = 46, OW = 46, pad = 2;
        int OWq = (OW + 3) / 4;
        int total = N * OC * OH * OWq;
        hipLaunchKernelGGL((conv_kernel<5, false>), dim3((total + 255) / 256), dim3(256), 0, stream,
                           B, F2, b2, A, N, IC, H, W, OC, OH, OW, pad, OWq);
    }
    // conv3 + pool: (64,48,46,46) -> (64,96,23,23), K=5, pad=2
    {
        int IC = 48, H = 46, W = 46, OC = 96, OH = 23, OW = 23, pad = 2;
        int OWq = (OW + 3) / 4;
        int total = N * OC * OH * OWq;
        hipLaunchKernelGGL((conv_kernel<5, true>), dim3((total + 255) / 256), dim3(256), 0, stream,
                           A, F3, b3, B, N, IC, H, W, OC, OH, OW, pad, OWq);
    }
    // conv4: (64,96,23,23) -> (64,96,23,23), K=5, pad=2
    {
        int IC = 96, H = 23, W = 23, OC = 96, OH = 23, OW = 23, pad = 2;
        int OWq = (OW + 3) / 4;
        int total = N * OC * OH * OWq;
        hipLaunchKernelGGL((conv_kernel<5, false>), dim3((total + 255) / 256), dim3(256), 0, stream,
                           B, F4, b4, A, N, IC, H, W, OC, OH, OW, pad, OWq);
    }
    // conv5: (64,96,23,23) -> (64,64,21,21), K=5, pad=1
    {
        int IC = 96, H = 23, W = 23, OC = 64, OH = 21, OW = 21, pad = 1;
        int OWq = (OW + 3) / 4;
        int total = N * OC * OH * OWq;
        hipLaunchKernelGGL((conv_kernel<5, false>), dim3((total + 255) / 256), dim3(256), 0, stream,
                           A, F5, b5, B, N, IC, H, W, OC, OH, OW, pad, OWq);
    }
    // mean over 21x21 -> (64,64)
    hipLaunchKernelGGL(mean_kernel, dim3(1024), dim3(256), 0, stream,
                       B, MEANB, 64 * 64, 21 * 21, 1.0f / 441.0f);
    // fc1 + relu + fc2 -> (64,10)
    hipLaunchKernelGGL(fc_kernel, dim3(1), dim3(256), 0, stream,
                       MEANB, fw1, fb1, fw2, fb2, (float*)d_out);
}

// Round 3
// 4866.805 us; speedup vs baseline: 3.1481x; 3.1481x over previous
//
#include <hip/hip_runtime.h>
#include <hip/hip_bf16.h>

// ---------------------------------------------------------------------------
// C4 equivariant CNN, fp32 direct conv, round 3: latency-bound fix.
//  - weights pre-transposed to [ic*K*K][OC] so 4 consecutive oc = one float4
//  - each thread computes a 4-oc x (OXB-x) register tile (pool: 4oc x 2x2*OXB)
//  - pool kernels load each unique input row once (t = dy+ky)
// Pipeline: transforms -> conv0..conv5 (pool fused in conv1/conv3) -> mean -> fc.
// ---------------------------------------------------------------------------

// dest[y][x] = src[sy][sx] for rot90^r (counterclockwise, numpy convention)
__device__ __forceinline__ void rot_src(int r, int K, int y, int x, int& sy, int& sx) {
    switch (r & 3) {
        case 0: sy = y;         sx = x;         break;
        case 1: sy = x;         sx = K - 1 - y; break;
        case 2: sy = K - 1 - y; sx = K - 1 - x; break;
        default: sy = K - 1 - x; sx = y;        break;
    }
}

// w0: (6,1,7,7) -> F0T: [49][24];  F0T[y*7+x][o*4+r] = rot_r(w0[o])[y][x]
__global__ void lift_w0T_kernel(const float* __restrict__ w, float* __restrict__ f) {
    const int K = 7, KK = 49, OC = 24;
    int idx = blockIdx.x * blockDim.x + threadIdx.x;
    if (idx >= KK * OC) return;
    int oc = idx % OC; int kk = idx / OC;
    int y = kk / K, x = kk % K;
    int r = oc & 3, o = oc >> 2;
    int sy, sx; rot_src(r, K, y, x, sy, sx);
    f[idx] = w[o * KK + sy * K + sx];
}

// w: (O,I,4,5,5) -> FT: [(i*4+s)*25 + y*5+x][o*4+r] = rot_r(w[o][i][(s-r)%4])[y][x]
__global__ void group_wT_kernel(const float* __restrict__ w, float* __restrict__ f,
                                int O, int I) {
    const int K = 5, KK = 25;
    int OC = O * 4;
    int idx = blockIdx.x * blockDim.x + threadIdx.x;
    int total = I * 4 * KK * OC;
    if (idx >= total) return;
    int oc = idx % OC; int rest = idx / OC;
    int kk = rest % KK; int icg = rest / KK;
    int y = kk / K, x = kk % K;
    int s = icg & 3, i = icg >> 2;
    int r = oc & 3, o = oc >> 2;
    int g = (s - r + 4) & 3;
    int sy, sx; rot_src(r, K, y, x, sy, sx);
    f[idx] = w[(((o * I + i) * 4 + g) * KK) + sy * K + sx];
}

// Direct conv (cross-correlation), transposed weights wt[ic*K*K][OC],
// bias per group (all 4 oc of a quad share bias[ocq]), ReLU fused.
// !POOL: thread -> 4 oc x OXB x at one (n,oy).
// POOL : thread -> 4 oc x OXB pooled x at one (n,py); computes 2 x 2*OXB conv
//        patch per oc, maxes 2x2 windows. Unique input rows t=dy+ky loaded once.
template <int K, int OXB, bool POOL>
__global__ __launch_bounds__(256) void conv_t_kernel(
        const float* __restrict__ in, const float* __restrict__ wt,
        const float* __restrict__ bias, float* __restrict__ out,
        int N, int IC, int H, int W,
        int OC, int OH, int OW, int pad, int OCq, int OWq) {
    const int KK = K * K;
    int idx = blockIdx.x * blockDim.x + threadIdx.x;
    int total = N * OCq * OH * OWq;
    if (idx >= total) return;
    int xq = idx % OWq; int t = idx / OWq;
    int oy = t % OH; t /= OH;
    int ocq = t % OCq; int n = t / OCq;
    int oc0 = ocq * 4;
    float bv = bias[ocq];

    if constexpr (!POOL) {
        constexpr int XW = OXB + K - 1;
        int ox0 = xq * OXB;
        float acc[4][OXB];
#pragma unroll
        for (int a = 0; a < 4; ++a)
#pragma unroll
            for (int b = 0; b < OXB; ++b) acc[a][b] = 0.f;

        for (int ic = 0; ic < IC; ++ic) {
            const float* ip = in + (size_t)((n * IC + ic) * H) * W;
            const float* wp = wt + (size_t)ic * KK * OC + oc0;
#pragma unroll
            for (int ky = 0; ky < K; ++ky) {
                int iy = oy + ky - pad;
                if (iy < 0 || iy >= H) continue;
                const float* row = ip + (size_t)iy * W;
                float xv[XW];
#pragma unroll
                for (int u = 0; u < XW; ++u) {
                    int ix = ox0 - pad + u;
                    xv[u] = (ix >= 0 && ix < W) ? row[ix] : 0.f;
                }
#pragma unroll
                for (int kx = 0; kx < K; ++kx) {
                    float4 wv = *reinterpret_cast<const float4*>(wp + (ky * K + kx) * OC);
#pragma unroll
                    for (int jx = 0; jx < OXB; ++jx) {
                        acc[0][jx] = fmaf(wv.x, xv[kx + jx], acc[0][jx]);
                        acc[1][jx] = fmaf(wv.y, xv[kx + jx], acc[1][jx]);
                        acc[2][jx] = fmaf(wv.z, xv[kx + jx], acc[2][jx]);
                        acc[3][jx] = fmaf(wv.w, xv[kx + jx], acc[3][jx]);
                    }
                }
            }
        }
#pragma unroll
        for (int jo = 0; jo < 4; ++jo) {
            size_t ob = (size_t)((n * OC + oc0 + jo) * OH + oy) * OW + ox0;
#pragma unroll
            for (int jx = 0; jx < OXB; ++jx)
                if (ox0 + jx < OW) out[ob + jx] = fmaxf(acc[jo][jx] + bv, 0.f);
        }
    } else {
        constexpr int CX = 2 * OXB;          // conv columns computed
        constexpr int XW = CX + K - 1;
        int px0 = xq * OXB;
        int ox0 = px0 * 2;
        float acc[4][2][CX];
#pragma unroll
        for (int a = 0; a < 4; ++a)
#pragma unroll
            for (int d = 0; d < 2; ++d)
#pragma unroll
                for (int b = 0; b < CX; ++b) acc[a][d][b] = 0.f;

        for (int ic = 0; ic < IC; ++ic) {
            const float* ip = in + (size_t)((n * IC + ic) * H) * W;
            const float* wp = wt + (size_t)ic * KK * OC + oc0;
#pragma unroll
            for (int tt = 0; tt <= K; ++tt) {          // unique row offset dy+ky
                int iy = 2 * oy + tt - pad;
                if (iy < 0 || iy >= H) continue;
                const float* row = ip + (size_t)iy * W;
                float xv[XW];
#pragma unroll
                for (int u = 0; u < XW; ++u) {
                    int ix = ox0 - pad + u;
                    xv[u] = (ix >= 0 && ix < W) ? row[ix] : 0.f;
                }
#pragma unroll
                for (int dy = 0; dy < 2; ++dy) {
                    int ky = tt - dy;
                    if (ky < 0 || ky >= K) continue;   // folds at compile time
#pragma unroll
                    for (int kx = 0; kx < K; ++kx) {
                        float4 wv = *reinterpret_cast<const float4*>(wp + (ky * K + kx) * OC);
#pragma unroll
                        for (int jx = 0; jx < CX; ++jx) {
                            acc[0][dy][jx] = fmaf(wv.x, xv[kx + jx], acc[0][dy][jx]);
                            acc[1][dy][jx] = fmaf(wv.y, xv[kx + jx], acc[1][dy][jx]);
                            acc[2][dy][jx] = fmaf(wv.z, xv[kx + jx], acc[2][dy][jx]);
                            acc[3][dy][jx] = fmaf(wv.w, xv[kx + jx], acc[3][dy][jx]);
                        }
                    }
                }
            }
        }
#pragma unroll
        for (int jo = 0; jo < 4; ++jo) {
            size_t ob = (size_t)((n * OC + oc0 + jo) * OH + oy) * OW + px0;
#pragma unroll
            for (int j = 0; j < OXB; ++j) {
                if (px0 + j < OW) {
                    float m = fmaxf(fmaxf(acc[jo][0][2 * j], acc[jo][0][2 * j + 1]),
                                    fmaxf(acc[jo][1][2 * j], acc[jo][1][2 * j + 1]));
                    out[ob + j] = fmaxf(m + bv, 0.f);
                }
            }
        }
    }
}

// one wave per (n,c) channel: mean over HW
__global__ void mean_kernel(const float* __restrict__ in, float* __restrict__ out,
                            int NC, int HW, float inv) {
    int gid = blockIdx.x * blockDim.x + threadIdx.x;
    int wid = gid >> 6;
    int lane = threadIdx.x & 63;
    if (wid >= NC) return;
    const float* p = in + (size_t)wid * HW;
    float s = 0.f;
    for (int t = lane; t < HW; t += 64) s += p[t];
#pragma unroll
    for (int off = 32; off > 0; off >>= 1) s += __shfl_down(s, off, 64);
    if (lane == 0) out[wid] = s * inv;
}

// single block: fc1 (64x64, relu) then fc2 (10x64)
__global__ void fc_kernel(const float* __restrict__ mean, const float* __restrict__ fw1,
                          const float* __restrict__ fb1, const float* __restrict__ fw2,
                          const float* __restrict__ fb2, float* __restrict__ out) {
    __shared__ float m[4096];
    __shared__ float h1[4096];
    int tid = threadIdx.x;
    for (int i = tid; i < 4096; i += 256) m[i] = mean[i];
    __syncthreads();
    for (int i = tid; i < 4096; i += 256) {
        int n = i >> 6, j = i & 63;
        float s = fb1[j];
        for (int k = 0; k < 64; ++k) s = fmaf(m[n * 64 + k], fw1[j * 64 + k], s);
        h1[i] = fmaxf(s, 0.f);
    }
    __syncthreads();
    for (int i = tid; i < 640; i += 256) {
        int n = i / 10, j2 = i % 10;
        float s = fb2[j2];
        for (int j = 0; j < 64; ++j) s = fmaf(h1[n * 64 + j], fw2[j2 * 64 + j], s);
        out[i] = s;
    }
}

extern "C" void kernel_launch(void* const* d_in, const int* in_sizes, int n_in,
                              void* d_out, int out_size, void* d_ws, size_t ws_size,
                              hipStream_t stream) {
    const float* x   = (const float*)d_in[0];
    const float* w0  = (const float*)d_in[1];
    const float* b0  = (const float*)d_in[2];
    const float* w1  = (const float*)d_in[3];
    const float* b1  = (const float*)d_in[4];
    const float* w2  = (const float*)d_in[5];
    const float* b2  = (const float*)d_in[6];
    const float* w3  = (const float*)d_in[7];
    const float* b3  = (const float*)d_in[8];
    const float* w4  = (const float*)d_in[9];
    const float* b4  = (const float*)d_in[10];
    const float* w5  = (const float*)d_in[11];
    const float* b5  = (const float*)d_in[12];
    const float* fw1 = (const float*)d_in[13];
    const float* fb1 = (const float*)d_in[14];
    const float* fw2 = (const float*)d_in[15];
    const float* fb2 = (const float*)d_in[16];

    float* ws = (float*)d_ws;
    // transposed filter buffers (floats): F0 1176, F1 28800, F2 57600,
    // F3 115200, F4 230400, F5 153600
    float* F0 = ws + 0;
    float* F1 = ws + 1280;
    float* F2 = ws + 30080;
    float* F3 = ws + 87680;
    float* F4 = ws + 202880;
    float* F5 = ws + 433280;
    float* MEANB = ws + 586880;                // 4096 -> ends 590976
    // slot A: needs max(13000704 [conv0], 6500352 [conv2], 3250176 [conv4])
    float* A = ws + 591104;                    // ends 13,591,808
    // slot B: needs max(6500352 [conv1], 3250176 [conv3], 1806336 [conv5])
    float* B = ws + 13592064;                  // ends 20,092,416 (~76.6 MiB)

    // --- filter transforms (transposed layout [ic*K*K][OC]) ---
    hipLaunchKernelGGL(lift_w0T_kernel, dim3((24 * 49 + 255) / 256), dim3(256), 0, stream, w0, F0);
    auto gw = [&](const float* w, float* f, int O, int I) {
        int total = O * 4 * I * 4 * 25;
        hipLaunchKernelGGL(group_wT_kernel, dim3((total + 255) / 256), dim3(256), 0, stream, w, f, O, I);
    };
    gw(w1, F1, 12, 6);
    gw(w2, F2, 12, 12);
    gw(w3, F3, 24, 12);
    gw(w4, F4, 24, 24);
    gw(w5, F5, 16, 24);

    const int N = 64;

    // conv0: (64,1,96,96) -> (64,24,92,92), K=7, pad=1, OXB=4
    {
        int IC = 1, H = 96, W = 96, OC = 24, OH = 92, OW = 92, pad = 1;
        int OCq = OC / 4, OWq = (OW + 3) / 4;
        int total = N * OCq * OH * OWq;
        hipLaunchKernelGGL((conv_t_kernel<7, 4, false>), dim3((total + 255) / 256), dim3(256), 0, stream,
                           x, F0, b0, A, N, IC, H, W, OC, OH, OW, pad, OCq, OWq);
    }
    // conv1 + pool: (64,24,92,92) -> (64,48,46,46), K=5, pad=2, 2 pooled x/thread
    {
        int IC = 24, H = 92, W = 92, OC = 48, OH = 46, OW = 46, pad = 2;
        int OCq = OC / 4, OWq = (OW + 1) / 2;
        int total = N * OCq * OH * OWq;
        hipLaunchKernelGGL((conv_t_kernel<5, 2, true>), dim3((total + 255) / 256), dim3(256), 0, stream,
                           A, F1, b1, B, N, IC, H, W, OC, OH, OW, pad, OCq, OWq);
    }
    // conv2: (64,48,46,46) -> (64,48,46,46), K=5, pad=2, OXB=4
    {
        int IC = 48, H = 46, W = 46, OC = 48, OH = 46, OW = 46, pad = 2;
        int OCq = OC / 4, OWq = (OW + 3) / 4;
        int total = N * OCq * OH * OWq;
        hipLaunchKernelGGL((conv_t_kernel<5, 4, false>), dim3((total + 255) / 256), dim3(256), 0, stream,
                           B, F2, b2, A, N, IC, H, W, OC, OH, OW, pad, OCq, OWq);
    }
    // conv3 + pool: (64,48,46,46) -> (64,96,23,23), K=5, pad=2, 2 pooled x/thread
    {
        int IC = 48, H = 46, W = 46, OC = 96, OH = 23, OW = 23, pad = 2;
        int OCq = OC / 4, OWq = (OW + 1) / 2;
        int total = N * OCq * OH * OWq;
        hipLaunchKernelGGL((conv_t_kernel<5, 2, true>), dim3((total + 255) / 256), dim3(256), 0, stream,
                           A, F3, b3, B, N, IC, H, W, OC, OH, OW, pad, OCq, OWq);
    }
    // conv4: (64,96,23,23) -> (64,96,23,23), K=5, pad=2, OXB=2
    {
        int IC = 96, H = 23, W = 23, OC = 96, OH = 23, OW = 23, pad = 2;
        int OCq = OC / 4, OWq = (OW + 1) / 2;
        int total = N * OCq * OH * OWq;
        hipLaunchKernelGGL((conv_t_kernel<5, 2, false>), dim3((total + 255) / 256), dim3(256), 0, stream,
                           B, F4, b4, A, N, IC, H, W, OC, OH, OW, pad, OCq, OWq);
    }
    // conv5: (64,96,23,23) -> (64,64,21,21), K=5, pad=1, OXB=2
    {
        int IC = 96, H = 23, W = 23, OC = 64, OH = 21, OW = 21, pad = 1;
        int OCq = OC / 4, OWq = (OW + 1) / 2;
        int total = N * OCq * OH * OWq;
        hipLaunchKernelGGL((conv_t_kernel<5, 2, false>), dim3((total + 255) / 256), dim3(256), 0, stream,
                           A, F5, b5, B, N, IC, H, W, OC, OH, OW, pad, OCq, OWq);
    }
    // mean over 21x21 -> (64,64)
    hipLaunchKernelGGL(mean_kernel, dim3(1024), dim3(256), 0, stream,
                       B, MEANB, 64 * 64, 21 * 21, 1.0f / 441.0f);
    // fc1 + relu + fc2 -> (64,10)
    hipLaunchKernelGGL(fc_kernel, dim3(1), dim3(256), 0, stream,
                       MEANB, fw1, fb1, fw2, fb2, (float*)d_out);
}

// Round 4
// 3542.714 us; speedup vs baseline: 4.3247x; 1.3738x over previous
//
#include <hip/hip_runtime.h>
#include <hip/hip_bf16.h>

// ---------------------------------------------------------------------------
// C4 equivariant CNN, fp32 direct conv, round 4: branch-free padded buffers.
//  - every intermediate stored zero-padded to its consumer's halo, width %4
//  - all conv input loads are float4, no bounds branches anywhere in the loop
//  - weights pre-transposed to [ic*K*K][OC]: 4 oc = one float4
//  - pool fused (conv1/conv3), unique input rows loaded once
//  - memsetAsync re-zeroes each padded dst region in stream order (A/B reuse)
// ---------------------------------------------------------------------------

__device__ __forceinline__ void rot_src(int r, int K, int y, int x, int& sy, int& sx) {
    switch (r & 3) {
        case 0: sy = y;         sx = x;         break;
        case 1: sy = x;         sx = K - 1 - y; break;
        case 2: sy = K - 1 - y; sx = K - 1 - x; break;
        default: sy = K - 1 - x; sx = y;        break;
    }
}

// w0: (6,1,7,7) -> F0T: [49][24]
__global__ void lift_w0T_kernel(const float* __restrict__ w, float* __restrict__ f) {
    const int K = 7, KK = 49, OC = 24;
    int idx = blockIdx.x * blockDim.x + threadIdx.x;
    if (idx >= KK * OC) return;
    int oc = idx % OC; int kk = idx / OC;
    int y = kk / K, x = kk % K;
    int r = oc & 3, o = oc >> 2;
    int sy, sx; rot_src(r, K, y, x, sy, sx);
    f[idx] = w[o * KK + sy * K + sx];
}

// w: (O,I,4,5,5) -> FT: [(i*4+s)*25 + y*5+x][o*4+r]
__global__ void group_wT_kernel(const float* __restrict__ w, float* __restrict__ f,
                                int O, int I) {
    const int K = 5, KK = 25;
    int OC = O * 4;
    int idx = blockIdx.x * blockDim.x + threadIdx.x;
    int total = I * 4 * KK * OC;
    if (idx >= total) return;
    int oc = idx % OC; int rest = idx / OC;
    int kk = rest % KK; int icg = rest / KK;
    int y = kk / K, x = kk % K;
    int s = icg & 3, i = icg >> 2;
    int r = oc & 3, o = oc >> 2;
    int g = (s - r + 4) & 3;
    int sy, sx; rot_src(r, K, y, x, sy, sx);
    f[idx] = w[(((o * I + i) * 4 + g) * KK) + sy * K + sx];
}

// x (64,1,96,96) -> xp (64, 98, 100) with 1-border (zeroed beforehand)
__global__ void pad_x_kernel(const float* __restrict__ x, float* __restrict__ xp) {
    int idx = blockIdx.x * blockDim.x + threadIdx.x;
    if (idx >= 64 * 96 * 96) return;
    int c = idx % 96; int t = idx / 96;
    int r = t % 96; int n = t / 96;
    xp[((size_t)n * 98 + r + 1) * 100 + c + 1] = x[idx];
}

// Branch-free padded conv. Input: padded planes [IC][Hp][Wp], halo == this
// conv's pad, Wp%4==0. Output written at (+padN,+padN) into [OC][Hpo][Wpo].
// !POOL: thread -> 4 oc x OXB x.   POOL: thread -> 4 oc x 2 pooled x (CX=4).
template <int K, int OXB, bool POOL>
__global__ __launch_bounds__(256) void conv_p_kernel(
        const float* __restrict__ in, const float* __restrict__ wt,
        const float* __restrict__ bias, float* __restrict__ out,
        int N, int IC, int Hp, int Wp,
        int OC, int OCq, int OH, int OW, int OWq,
        int Hpo, int Wpo, int padN) {
    const int KK = K * K;
    int idx = blockIdx.x * blockDim.x + threadIdx.x;
    int total = N * OCq * OH * OWq;
    if (idx >= total) return;
    int xq = idx % OWq; int t = idx / OWq;
    int oy = t % OH; t /= OH;
    int ocq = t % OCq; int n = t / OCq;
    int oc0 = ocq * 4;
    float bv = bias[ocq];

    if constexpr (!POOL) {
        constexpr int XWV = (OXB + K - 1 + 3) / 4;   // float4 loads per row
        int ox0 = xq * OXB;                           // multiple of 4
        float acc[4][OXB];
#pragma unroll
        for (int a = 0; a < 4; ++a)
#pragma unroll
            for (int b = 0; b < OXB; ++b) acc[a][b] = 0.f;

        const float* ip = in + ((size_t)(n * IC) * Hp + oy) * Wp + ox0;
        const float* wp = wt + oc0;
        for (int ic = 0; ic < IC; ++ic) {
            const float* icp = ip + (size_t)ic * Hp * Wp;
            const float* wcp = wp + (size_t)ic * KK * OC;
#pragma unroll
            for (int ky = 0; ky < K; ++ky) {
                const float* row = icp + (size_t)ky * Wp;
                float xv[XWV * 4];
#pragma unroll
                for (int v = 0; v < XWV; ++v)
                    *reinterpret_cast<float4*>(&xv[4 * v]) =
                        *reinterpret_cast<const float4*>(row + 4 * v);
#pragma unroll
                for (int kx = 0; kx < K; ++kx) {
                    float4 wv = *reinterpret_cast<const float4*>(wcp + (ky * K + kx) * OC);
#pragma unroll
                    for (int jx = 0; jx < OXB; ++jx) {
                        acc[0][jx] = fmaf(wv.x, xv[kx + jx], acc[0][jx]);
                        acc[1][jx] = fmaf(wv.y, xv[kx + jx], acc[1][jx]);
                        acc[2][jx] = fmaf(wv.z, xv[kx + jx], acc[2][jx]);
                        acc[3][jx] = fmaf(wv.w, xv[kx + jx], acc[3][jx]);
                    }
                }
            }
        }
#pragma unroll
        for (int jo = 0; jo < 4; ++jo) {
            size_t ob = ((size_t)(n * OC + oc0 + jo) * Hpo + oy + padN) * Wpo + ox0 + padN;
#pragma unroll
            for (int jx = 0; jx < OXB; ++jx)
                if (ox0 + jx < OW) out[ob + jx] = fmaxf(acc[jo][jx] + bv, 0.f);
        }
    } else {
        // 2 pooled x per thread; conv patch 2 rows x 8 cols, window float4-aligned
        int px0 = xq * 2;
        int ox0 = xq * 4;
        float acc[4][2][4];
#pragma unroll
        for (int a = 0; a < 4; ++a)
#pragma unroll
            for (int d = 0; d < 2; ++d)
#pragma unroll
                for (int b = 0; b < 4; ++b) acc[a][d][b] = 0.f;

        const float* ip = in + ((size_t)(n * IC) * Hp + 2 * oy) * Wp + ox0;
        const float* wp = wt + oc0;
        for (int ic = 0; ic < IC; ++ic) {
            const float* icp = ip + (size_t)ic * Hp * Wp;
            const float* wcp = wp + (size_t)ic * KK * OC;
#pragma unroll
            for (int tt = 0; tt <= K; ++tt) {          // unique row offset dy+ky
                const float* row = icp + (size_t)tt * Wp;
                float xv[8];
                *reinterpret_cast<float4*>(&xv[0]) = *reinterpret_cast<const float4*>(row);
                *reinterpret_cast<float4*>(&xv[4]) = *reinterpret_cast<const float4*>(row + 4);
#pragma unroll
                for (int dy = 0; dy < 2; ++dy) {
                    int ky = tt - dy;                  // compile-time folded
                    if (ky < 0 || ky >= K) continue;
#pragma unroll
                    for (int kx = 0; kx < K; ++kx) {
                        float4 wv = *reinterpret_cast<const float4*>(wcp + (ky * K + kx) * OC);
#pragma unroll
                        for (int jx = 0; jx < 4; ++jx) {
                            acc[0][dy][jx] = fmaf(wv.x, xv[kx + jx], acc[0][dy][jx]);
                            acc[1][dy][jx] = fmaf(wv.y, xv[kx + jx], acc[1][dy][jx]);
                            acc[2][dy][jx] = fmaf(wv.z, xv[kx + jx], acc[2][dy][jx]);
                            acc[3][dy][jx] = fmaf(wv.w, xv[kx + jx], acc[3][dy][jx]);
                        }
                    }
                }
            }
        }
#pragma unroll
        for (int jo = 0; jo < 4; ++jo) {
            size_t ob = ((size_t)(n * OC + oc0 + jo) * Hpo + oy + padN) * Wpo + px0 + padN;
#pragma unroll
            for (int j = 0; j < 2; ++j) {
                if (px0 + j < OW) {
                    float m = fmaxf(fmaxf(acc[jo][0][2 * j], acc[jo][0][2 * j + 1]),
                                    fmaxf(acc[jo][1][2 * j], acc[jo][1][2 * j + 1]));
                    out[ob + j] = fmaxf(m + bv, 0.f);
                }
            }
        }
    }
}

// one wave per (n,c) channel: mean over HW (compact input)
__global__ void mean_kernel(const float* __restrict__ in, float* __restrict__ out,
                            int NC, int HW, float inv) {
    int gid = blockIdx.x * blockDim.x + threadIdx.x;
    int wid = gid >> 6;
    int lane = threadIdx.x & 63;
    if (wid >= NC) return;
    const float* p = in + (size_t)wid * HW;
    float s = 0.f;
    for (int t = lane; t < HW; t += 64) s += p[t];
#pragma unroll
    for (int off = 32; off > 0; off >>= 1) s += __shfl_down(s, off, 64);
    if (lane == 0) out[wid] = s * inv;
}

// single block: fc1 (64x64, relu) then fc2 (10x64)
__global__ void fc_kernel(const float* __restrict__ mean, const float* __restrict__ fw1,
                          const float* __restrict__ fb1, const float* __restrict__ fw2,
                          const float* __restrict__ fb2, float* __restrict__ out) {
    __shared__ float m[4096];
    __shared__ float h1[4096];
    int tid = threadIdx.x;
    for (int i = tid; i < 4096; i += 256) m[i] = mean[i];
    __syncthreads();
    for (int i = tid; i < 4096; i += 256) {
        int n = i >> 6, j = i & 63;
        float s = fb1[j];
        for (int k = 0; k < 64; ++k) s = fmaf(m[n * 64 + k], fw1[j * 64 + k], s);
        h1[i] = fmaxf(s, 0.f);
    }
    __syncthreads();
    for (int i = tid; i < 640; i += 256) {
        int n = i / 10, j2 = i % 10;
        float s = fb2[j2];
        for (int j = 0; j < 64; ++j) s = fmaf(h1[n * 64 + j], fw2[j2 * 64 + j], s);
        out[i] = s;
    }
}

extern "C" void kernel_launch(void* const* d_in, const int* in_sizes, int n_in,
                              void* d_out, int out_size, void* d_ws, size_t ws_size,
                              hipStream_t stream) {
    const float* x   = (const float*)d_in[0];
    const float* w0  = (const float*)d_in[1];
    const float* b0  = (const float*)d_in[2];
    const float* w1  = (const float*)d_in[3];
    const float* b1  = (const float*)d_in[4];
    const float* w2  = (const float*)d_in[5];
    const float* b2  = (const float*)d_in[6];
    const float* w3  = (const float*)d_in[7];
    const float* b3  = (const float*)d_in[8];
    const float* w4  = (const float*)d_in[9];
    const float* b4  = (const float*)d_in[10];
    const float* w5  = (const float*)d_in[11];
    const float* b5  = (const float*)d_in[12];
    const float* fw1 = (const float*)d_in[13];
    const float* fb1 = (const float*)d_in[14];
    const float* fw2 = (const float*)d_in[15];
    const float* fb2 = (const float*)d_in[16];

    float* ws = (float*)d_ws;
    // transposed filters
    float* F0 = ws + 0;          // 1176 (reserve 1280)
    float* F1 = ws + 1280;       // 28800
    float* F2 = ws + 30080;      // 57600
    float* F3 = ws + 87680;      // 115200
    float* F4 = ws + 202880;     // 230400
    float* F5 = ws + 433280;     // 153600
    float* MEANB = ws + 586880;  // 4096 -> 590976
    // slot A: A0 (64*24*96*96=14,155,776) / A2 (64*48*50*52=7,987,200) /
    //         A4 (64*96*25*28=4,300,800)
    float* A = ws + 591104;      // end 14,746,880
    // slot B: B1 (64*48*50*52=7,987,200) / B3 (64*96*27*28=4,644,864) /
    //         B5 (64*64*441=1,806,336).  Xpad (64*98*100=627,200) aliases B
    //         (dead before conv1 writes B1).
    float* B = ws + 14746880;    // end 22,734,080 floats (~86.7 MiB used)
    float* XP = B;

    // --- filter transforms ---
    hipLaunchKernelGGL(lift_w0T_kernel, dim3((24 * 49 + 255) / 256), dim3(256), 0, stream, w0, F0);
    auto gw = [&](const float* w, float* f, int O, int I) {
        int total = O * 4 * I * 4 * 25;
        hipLaunchKernelGGL(group_wT_kernel, dim3((total + 255) / 256), dim3(256), 0, stream, w, f, O, I);
    };
    gw(w1, F1, 12, 6);
    gw(w2, F2, 12, 12);
    gw(w3, F3, 24, 12);
    gw(w4, F4, 24, 24);
    gw(w5, F5, 16, 24);

    const int N = 64;

    // pad input: (64,96,96) -> XP (64,98,100), border 1
    hipMemsetAsync(XP, 0, (size_t)627200 * 4, stream);
    hipLaunchKernelGGL(pad_x_kernel, dim3((589824 + 255) / 256), dim3(256), 0, stream, x, XP);

    // conv0: XP -> A0 [24][96][96] (halo 2 for conv1), K=7, OXB=4
    hipMemsetAsync(A, 0, (size_t)14155776 * 4, stream);
    {
        int IC = 1, Hp = 98, Wp = 100, OC = 24, OH = 92, OW = 92;
        int OCq = 6, OWq = 23;
        int total = N * OCq * OH * OWq;
        hipLaunchKernelGGL((conv_p_kernel<7, 4, false>), dim3((total + 255) / 256), dim3(256), 0, stream,
                           XP, F0, b0, A, N, IC, Hp, Wp, OC, OCq, OH, OW, OWq, 96, 96, 2);
    }
    // conv1+pool: A0 -> B1 [48][50][52] (halo 2), K=5
    hipMemsetAsync(B, 0, (size_t)7987200 * 4, stream);
    {
        int IC = 24, Hp = 96, Wp = 96, OC = 48, OH = 46, OW = 46;
        int OCq = 12, OWq = 23;
        int total = N * OCq * OH * OWq;
        hipLaunchKernelGGL((conv_p_kernel<5, 2, true>), dim3((total + 255) / 256), dim3(256), 0, stream,
                           A, F1, b1, B, N, IC, Hp, Wp, OC, OCq, OH, OW, OWq, 50, 52, 2);
    }
    // conv2: B1 -> A2 [48][50][52] (halo 2), K=5, OXB=4
    hipMemsetAsync(A, 0, (size_t)7987200 * 4, stream);
    {
        int IC = 48, Hp = 50, Wp = 52, OC = 48, OH = 46, OW = 46;
        int OCq = 12, OWq = 12;
        int total = N * OCq * OH * OWq;
        hipLaunchKernelGGL((conv_p_kernel<5, 4, false>), dim3((total + 255) / 256), dim3(256), 0, stream,
                           B, F2, b2, A, N, IC, Hp, Wp, OC, OCq, OH, OW, OWq, 50, 52, 2);
    }
    // conv3+pool: A2 -> B3 [96][27][28] (halo 2), K=5
    hipMemsetAsync(B, 0, (size_t)4644864 * 4, stream);
    {
        int IC = 48, Hp = 50, Wp = 52, OC = 96, OH = 23, OW = 23;
        int OCq = 24, OWq = 12;
        int total = N * OCq * OH * OWq;
        hipLaunchKernelGGL((conv_p_kernel<5, 2, true>), dim3((total + 255) / 256), dim3(256), 0, stream,
                           A, F3, b3, B, N, IC, Hp, Wp, OC, OCq, OH, OW, OWq, 27, 28, 2);
    }
    // conv4: B3 -> A4 [96][25][28] (halo 1 for conv5), K=5, OXB=4
    hipMemsetAsync(A, 0, (size_t)4300800 * 4, stream);
    {
        int IC = 96, Hp = 27, Wp = 28, OC = 96, OH = 23, OW = 23;
        int OCq = 24, OWq = 6;
        int total = N * OCq * OH * OWq;
        hipLaunchKernelGGL((conv_p_kernel<5, 4, false>), dim3((total + 255) / 256), dim3(256), 0, stream,
                           B, F4, b4, A, N, IC, Hp, Wp, OC, OCq, OH, OW, OWq, 25, 28, 1);
    }
    // conv5: A4 -> B5 [64][21][21] compact, K=5, OXB=4
    {
        int IC = 96, Hp = 25, Wp = 28, OC = 64, OH = 21, OW = 21;
        int OCq = 16, OWq = 6;
        int total = N * OCq * OH * OWq;
        hipLaunchKernelGGL((conv_p_kernel<5, 4, false>), dim3((total + 255) / 256), dim3(256), 0, stream,
                           A, F5, b5, B, N, IC, Hp, Wp, OC, OCq, OH, OW, OWq, 21, 21, 0);
    }
    // mean over 21x21 -> (64,64)
    hipLaunchKernelGGL(mean_kernel, dim3(1024), dim3(256), 0, stream,
                       B, MEANB, 64 * 64, 21 * 21, 1.0f / 441.0f);
    // fc1 + relu + fc2 -> (64,10)
    hipLaunchKernelGGL(fc_kernel, dim3(1), dim3(256), 0, stream,
                       MEANB, fw1, fb1, fw2, fb2, (float*)d_out);
}

// Round 5
// 862.042 us; speedup vs baseline: 17.7732x; 4.1097x over previous
//
#include <hip/hip_runtime.h>
#include <hip/hip_bf16.h>

// ---------------------------------------------------------------------------
// C4 equivariant CNN, round 5: conv1..conv5 as MFMA implicit-GEMM with
// split-bf16 (hi/lo) operands for fp32-like accuracy at matrix-core speed.
//   activations: NHWC bf16 hi|lo, zero-padded halo 2, IC rounded to 32
//   weights:     pre-packed B-fragments (k=(lane>>4)*8+j, col=lane&15), hi|lo
//   kernel:      per (n, row[, x-strip]) block; LDS chunk-major A tile;
//                per-wave MT x NTW register tile, 2 acc chains (P, Q);
//                3 MFMAs per k-chunk: ah*bh -> P, ah*bl -> Q, al*bh -> Q
//   pool fused into conv1/conv3 (2 conv rows per wave, max in epilogue)
//   conv0 (IC=1) stays fp32 vector; mean/fc unchanged.
// ---------------------------------------------------------------------------

typedef short s16x8 __attribute__((ext_vector_type(8)));
typedef __bf16 bf16x8 __attribute__((ext_vector_type(8)));
typedef float f32x4 __attribute__((ext_vector_type(4)));
typedef unsigned short u16;

__device__ __forceinline__ u16 f2bf(float f) {      // RNE fp32 -> bf16 bits
    unsigned u = __float_as_uint(f);
    return (u16)((u + 0x7FFFu + ((u >> 16) & 1u)) >> 16);
}
__device__ __forceinline__ float bf2f(u16 h) {
    return __uint_as_float(((unsigned)h) << 16);
}

__device__ __forceinline__ void rot_src(int r, int K, int y, int x, int& sy, int& sx) {
    switch (r & 3) {
        case 0: sy = y;         sx = x;         break;
        case 1: sy = x;         sx = K - 1 - y; break;
        case 2: sy = K - 1 - y; sx = K - 1 - x; break;
        default: sy = K - 1 - x; sx = y;        break;
    }
}

// w0: (6,1,7,7) -> F0T: [49][24] fp32 (for fp32 conv0)
__global__ void lift_w0T_kernel(const float* __restrict__ w, float* __restrict__ f) {
    const int K = 7, KK = 49, OC = 24;
    int idx = blockIdx.x * blockDim.x + threadIdx.x;
    if (idx >= KK * OC) return;
    int oc = idx % OC; int kk = idx / OC;
    int y = kk / K, x = kk % K;
    int r = oc & 3, o = oc >> 2;
    int sy, sx; rot_src(r, K, y, x, sy, sx);
    f[idx] = w[o * KK + sy * K + sx];
}

// group-transform + split + pack into MFMA B-fragment order.
// layout: elem idx = (((kpos*KC + kc)*NT + nc)*64 + lane)*8 + j
//   k (channel) = kc*32 + (lane>>4)*8 + j ; oc = nc*16 + (lane&15)
// hi at [idx], lo at [idx + total].
__global__ void wfrag_kernel(const float* __restrict__ w, u16* __restrict__ wf,
                             int O, int I, int KC, int NT, int total) {
    int idx = blockIdx.x * blockDim.x + threadIdx.x;
    if (idx >= total) return;
    int j = idx & 7;
    int lane = (idx >> 3) & 63;
    int rest = idx >> 9;
    int nc = rest % NT; rest /= NT;
    int kc = rest % KC; int kpos = rest / KC;
    int ky = kpos / 5, kx = kpos % 5;
    int kk = ((lane >> 4) << 3) + j;
    int ic = kc * 32 + kk;
    int oc = nc * 16 + (lane & 15);
    float val = 0.f;
    if (ic < I * 4) {
        int o = oc >> 2, r = oc & 3, i = ic >> 2, s = ic & 3;
        int g = (s - r + 4) & 3;
        int sy, sx; rot_src(r, 5, ky, kx, sy, sx);
        val = w[(((o * I + i) * 4 + g) * 25) + sy * 5 + sx];
    }
    u16 hb = f2bf(val);
    u16 lb = f2bf(val - bf2f(hb));
    wf[idx] = hb;
    wf[idx + total] = lb;
}

// x (64,1,96,96) -> xp (64, 98, 100) fp32 with 1-border (pre-zeroed)
__global__ void pad_x_kernel(const float* __restrict__ x, float* __restrict__ xp) {
    int idx = blockIdx.x * blockDim.x + threadIdx.x;
    if (idx >= 64 * 96 * 96) return;
    int c = idx % 96; int t = idx / 96;
    int r = t % 96; int n = t / 96;
    xp[((size_t)n * 98 + r + 1) * 100 + c + 1] = x[idx];
}

// conv0: fp32 direct (IC=1, K=7, pad=1), epilogue -> P1 NHWC bf16 hi/lo
// P1: [64][96][96][32], halo 2, ch 24..31 zero (pre-memset).
__global__ __launch_bounds__(256) void conv0_kernel(
        const float* __restrict__ xp, const float* __restrict__ f0t,
        const float* __restrict__ b0, u16* __restrict__ p1, long p1LO) {
    int idx = blockIdx.x * blockDim.x + threadIdx.x;
    if (idx >= 64 * 6 * 92 * 23) return;
    int xq = idx % 23; int t = idx / 23;
    int oy = t % 92; t /= 92;
    int ocq = t % 6; int n = t / 6;
    int ox0 = xq * 4;
    float acc[4][4];
#pragma unroll
    for (int a = 0; a < 4; ++a)
#pragma unroll
        for (int b = 0; b < 4; ++b) acc[a][b] = 0.f;

    const float* ip = xp + ((size_t)n * 98 + oy) * 100 + ox0;
#pragma unroll
    for (int ky = 0; ky < 7; ++ky) {
        const float* row = ip + (size_t)ky * 100;
        float xv[12];
#pragma unroll
        for (int v = 0; v < 3; ++v)
            *reinterpret_cast<float4*>(&xv[4 * v]) =
                *reinterpret_cast<const float4*>(row + 4 * v);
#pragma unroll
        for (int kx = 0; kx < 7; ++kx) {
            float4 wv = *reinterpret_cast<const float4*>(f0t + (ky * 7 + kx) * 24 + ocq * 4);
#pragma unroll
            for (int jx = 0; jx < 4; ++jx) {
                acc[0][jx] = fmaf(wv.x, xv[kx + jx], acc[0][jx]);
                acc[1][jx] = fmaf(wv.y, xv[kx + jx], acc[1][jx]);
                acc[2][jx] = fmaf(wv.z, xv[kx + jx], acc[2][jx]);
                acc[3][jx] = fmaf(wv.w, xv[kx + jx], acc[3][jx]);
            }
        }
    }
    float bv = b0[ocq];
#pragma unroll
    for (int jo = 0; jo < 4; ++jo)
#pragma unroll
        for (int jx = 0; jx < 4; ++jx) {
            float v = fmaxf(acc[jo][jx] + bv, 0.f);
            u16 hb = f2bf(v);
            u16 lb = f2bf(v - bf2f(hb));
            size_t o = (((size_t)n * 96 + oy + 2) * 96 + ox0 + jx + 2) * 32 + ocq * 4 + jo;
            p1[o] = hb; p1[o + p1LO] = lb;
        }
}

// ---------------------------------------------------------------------------
// MFMA conv. Template: IC32 (padded in-ch), NT (OC/16), MT (x subtiles),
// NTW (nc per wave), WT (staged cols), POOL, XOFF (=2-pad).
// Block: one (n, out-row[, x-strip]); waves: nc strips, MT x-subtiles each.
// ---------------------------------------------------------------------------
template <int IC32, int NT, int MT, int NTW, int WT, bool POOL, int XOFF>
__global__ __launch_bounds__(256) void conv_mfma_kernel(
        const u16* __restrict__ act, long actLO,
        const u16* __restrict__ wf, int wfLO,
        const float* __restrict__ bias,
        u16* __restrict__ outP, long outLO,
        float* __restrict__ outF,
        int Hp, int Wp, int OHb, int OW,
        int xbase, int gx0base, int gx0last,
        int HpO, int WpO, int IC32O, int OWO) {
    constexpr int KC = IC32 / 32;
    constexpr int KC4 = IC32 / 8;          // 16B chunks per x per split
    constexpr int R = POOL ? 6 : 5;
    constexpr int RW = R * WT;
    constexpr int CST = RW + ((2 - (RW % 8) + 8) % 8);  // chunk stride, ≡2 mod 8
    constexpr int ROWS = POOL ? 2 : 1;
    __shared__ u16 lds[2 * KC4 * CST * 8];

    int oy = blockIdx.x % OHb;
    int n = blockIdx.x / OHb;
    int rbase = (POOL ? 2 * oy : oy) + XOFF;

    // stage A tile (hi|lo), chunk-major [sp*KC4+cc][row][x] of 16B chunks
    const int CH = 2 * KC4;
    for (int u = threadIdx.x; u < RW * CH; u += blockDim.x) {
        int c = u % CH; int rx = u / CH;
        int x = rx % WT, row = rx / WT;
        int sp = c / KC4, cc = c % KC4;
        int gx = xbase + x;
        s16x8 v = {0, 0, 0, 0, 0, 0, 0, 0};
        if (gx < Wp)
            v = *(const s16x8*)(act + (size_t)sp * actLO +
                  (((size_t)n * Hp + rbase + row) * Wp + gx) * IC32 + cc * 8);
        *(s16x8*)&lds[((size_t)(sp * KC4 + cc) * CST + row * WT + x) * 8] = v;
    }
    __syncthreads();

    int wv = threadIdx.x >> 6;
    int lane = threadIdx.x & 63;
    int l15 = lane & 15, lg = lane >> 4;

    int rd0[MT];
#pragma unroll
    for (int m = 0; m < MT; ++m) {
        int gx0 = (m == MT - 1) ? gx0last : gx0base + m * 16;
        rd0[m] = gx0 - xbase + XOFF + l15;
    }

    f32x4 accP[ROWS][MT][NTW], accQ[ROWS][MT][NTW];
#pragma unroll
    for (int rw = 0; rw < ROWS; ++rw)
#pragma unroll
        for (int m = 0; m < MT; ++m)
#pragma unroll
            for (int ncw = 0; ncw < NTW; ++ncw) {
                accP[rw][m][ncw] = f32x4{0.f, 0.f, 0.f, 0.f};
                accQ[rw][m][ncw] = f32x4{0.f, 0.f, 0.f, 0.f};
            }

    const u16* wfw = wf + (size_t)lane * 8;

    for (int kpos = 0; kpos < 25; ++kpos) {
        int ky = kpos / 5, kx = kpos % 5;
#pragma unroll
        for (int kc = 0; kc < KC; ++kc) {
            int cc = kc * 4 + lg;
            bf16x8 af[ROWS][MT][2];
#pragma unroll
            for (int m = 0; m < MT; ++m) {
                const u16* lA = &lds[((size_t)cc * CST + ky * WT + rd0[m] + kx) * 8];
#pragma unroll
                for (int rw = 0; rw < ROWS; ++rw) {
                    af[rw][m][0] = *(const bf16x8*)(lA + rw * WT * 8);
                    af[rw][m][1] = *(const bf16x8*)(lA + ((size_t)KC4 * CST + rw * WT) * 8);
                }
            }
#pragma unroll
            for (int ncw = 0; ncw < NTW; ++ncw) {
                int nc = wv * NTW + ncw;
                const u16* bp = wfw + ((size_t)(kpos * KC + kc) * NT + nc) * 512;
                bf16x8 bh = *(const bf16x8*)bp;
                bf16x8 bl = *(const bf16x8*)(bp + wfLO);
#pragma unroll
                for (int m = 0; m < MT; ++m)
#pragma unroll
                    for (int rw = 0; rw < ROWS; ++rw) {
                        accP[rw][m][ncw] = __builtin_amdgcn_mfma_f32_16x16x32_bf16(
                            af[rw][m][0], bh, accP[rw][m][ncw], 0, 0, 0);
                        accQ[rw][m][ncw] = __builtin_amdgcn_mfma_f32_16x16x32_bf16(
                            af[rw][m][0], bl, accQ[rw][m][ncw], 0, 0, 0);
                        accQ[rw][m][ncw] = __builtin_amdgcn_mfma_f32_16x16x32_bf16(
                            af[rw][m][1], bh, accQ[rw][m][ncw], 0, 0, 0);
                    }
            }
        }
    }

    // epilogue: C layout col=lane&15 (oc), row=(lane>>4)*4+j (x)
#pragma unroll
    for (int ncw = 0; ncw < NTW; ++ncw) {
        int oc = (wv * NTW + ncw) * 16 + l15;
        float bv = bias[oc >> 2];
#pragma unroll
        for (int m = 0; m < MT; ++m) {
            int gx0 = (m == MT - 1) ? gx0last : gx0base + m * 16;
            if constexpr (POOL) {
                float c0[4], c1[4];
#pragma unroll
                for (int j = 0; j < 4; ++j) {
                    c0[j] = accP[0][m][ncw][j] + accQ[0][m][ncw][j];
                    c1[j] = accP[1][m][ncw][j] + accQ[1][m][ncw][j];
                }
#pragma unroll
                for (int a2 = 0; a2 < 2; ++a2) {
                    float mx = fmaxf(fmaxf(c0[2 * a2], c0[2 * a2 + 1]),
                                     fmaxf(c1[2 * a2], c1[2 * a2 + 1]));
                    int xo = (gx0 + lg * 4 + 2 * a2) >> 1;
                    if (xo < OWO) {
                        float v = fmaxf(mx + bv, 0.f);
                        u16 hb = f2bf(v);
                        u16 lb = f2bf(v - bf2f(hb));
                        size_t o = (((size_t)n * HpO + oy + 2) * WpO + xo + 2) * IC32O + oc;
                        outP[o] = hb; outP[o + outLO] = lb;
                    }
                }
            } else {
#pragma unroll
                for (int j = 0; j < 4; ++j) {
                    int gx = gx0 + lg * 4 + j;
                    if (gx < OW) {
                        float v = fmaxf(accP[0][m][ncw][j] + accQ[0][m][ncw][j] + bv, 0.f);
                        if (outF) {
                            outF[(((size_t)n * OHb + oy) * OW + gx) * (NT * 16) + oc] = v;
                        } else {
                            u16 hb = f2bf(v);
                            u16 lb = f2bf(v - bf2f(hb));
                            size_t o = (((size_t)n * HpO + oy + 2) * WpO + gx + 2) * IC32O + oc;
                            outP[o] = hb; outP[o + outLO] = lb;
                        }
                    }
                }
            }
        }
    }
}

// mean over 21x21 spatial of NHWC fp32 [64][21][21][64] -> (64,64)
__global__ void mean_nhwc_kernel(const float* __restrict__ in, float* __restrict__ out) {
    __shared__ float sm[256];
    int n = blockIdx.x;
    int c = threadIdx.x & 63, q = threadIdx.x >> 6;
    float s = 0.f;
    for (int p = q; p < 441; p += 4) s += in[((size_t)n * 441 + p) * 64 + c];
    sm[threadIdx.x] = s;
    __syncthreads();
    if (q == 0) out[n * 64 + c] = (sm[c] + sm[c + 64] + sm[c + 128] + sm[c + 192]) * (1.0f / 441.0f);
}

// single block: fc1 (64x64, relu) then fc2 (10x64)
__global__ void fc_kernel(const float* __restrict__ mean, const float* __restrict__ fw1,
                          const float* __restrict__ fb1, const float* __restrict__ fw2,
                          const float* __restrict__ fb2, float* __restrict__ out) {
    __shared__ float m[4096];
    __shared__ float h1[4096];
    int tid = threadIdx.x;
    for (int i = tid; i < 4096; i += 256) m[i] = mean[i];
    __syncthreads();
    for (int i = tid; i < 4096; i += 256) {
        int n = i >> 6, j = i & 63;
        float s = fb1[j];
        for (int k = 0; k < 64; ++k) s = fmaf(m[n * 64 + k], fw1[j * 64 + k], s);
        h1[i] = fmaxf(s, 0.f);
    }
    __syncthreads();
    for (int i = tid; i < 640; i += 256) {
        int n = i / 10, j2 = i % 10;
        float s = fb2[j2];
        for (int j = 0; j < 64; ++j) s = fmaf(h1[n * 64 + j], fw2[j2 * 64 + j], s);
        out[i] = s;
    }
}

extern "C" void kernel_launch(void* const* d_in, const int* in_sizes, int n_in,
                              void* d_out, int out_size, void* d_ws, size_t ws_size,
                              hipStream_t stream) {
    const float* x   = (const float*)d_in[0];
    const float* w0  = (const float*)d_in[1];
    const float* b0  = (const float*)d_in[2];
    const float* w1  = (const float*)d_in[3];
    const float* b1  = (const float*)d_in[4];
    const float* w2  = (const float*)d_in[5];
    const float* b2  = (const float*)d_in[6];
    const float* w3  = (const float*)d_in[7];
    const float* b3  = (const float*)d_in[8];
    const float* w4  = (const float*)d_in[9];
    const float* b4  = (const float*)d_in[10];
    const float* w5  = (const float*)d_in[11];
    const float* b5  = (const float*)d_in[12];
    const float* fw1 = (const float*)d_in[13];
    const float* fb1 = (const float*)d_in[14];
    const float* fw2 = (const float*)d_in[15];
    const float* fb2 = (const float*)d_in[16];

    char* ws = (char*)d_ws;
    if (ws_size < 128827392ull) return;   // loud failure rather than corruption

    // byte offsets (all 256-aligned)
    float* F0   = (float*)(ws + 0);            // 4704 B (reserve 8192)
    u16*   WF1  = (u16*)(ws + 8192);           // 153600 B, LO 38400 elems
    u16*   WF2  = (u16*)(ws + 161792);         // 307200 B, LO 76800
    u16*   WF3  = (u16*)(ws + 468992);         // 614400 B, LO 153600
    u16*   WF4  = (u16*)(ws + 1083392);        // 921600 B, LO 230400
    u16*   WF5  = (u16*)(ws + 2004992);        // 614400 B, LO 153600
    float* MEANB= (float*)(ws + 2619392);      // 16384 B
    float* XP   = (float*)(ws + 2635776);      // 2508800 B
    float* C5   = (float*)(ws + 5144576);      // 7225344 B
    u16*   A    = (u16*)(ws + 12369920);       // slotA 75497472 B: P1 / P3 / P5
    u16*   B    = (u16*)(ws + 87867392);       // slotB 40960000 B: P2 / P4
    const long P1LO = 18874368;   // 64*96*96*32
    const long P2LO = 10240000;   // 64*50*50*64
    const long P4LO = 4478976;    // 64*27*27*96

    // --- weight transforms ---
    hipLaunchKernelGGL(lift_w0T_kernel, dim3(5), dim3(256), 0, stream, w0, F0);
    hipLaunchKernelGGL(wfrag_kernel, dim3(150), dim3(256), 0, stream, w1, WF1, 12, 6, 1, 3, 38400);
    hipLaunchKernelGGL(wfrag_kernel, dim3(300), dim3(256), 0, stream, w2, WF2, 12, 12, 2, 3, 76800);
    hipLaunchKernelGGL(wfrag_kernel, dim3(600), dim3(256), 0, stream, w3, WF3, 24, 12, 2, 6, 153600);
    hipLaunchKernelGGL(wfrag_kernel, dim3(900), dim3(256), 0, stream, w4, WF4, 24, 24, 3, 6, 230400);
    hipLaunchKernelGGL(wfrag_kernel, dim3(600), dim3(256), 0, stream, w5, WF5, 16, 24, 3, 4, 153600);

    // --- input pad (fp32) ---
    hipMemsetAsync(XP, 0, 2508800, stream);
    hipLaunchKernelGGL(pad_x_kernel, dim3(2304), dim3(256), 0, stream, x, XP);

    // --- conv0 -> P1 (A) ---
    hipMemsetAsync(A, 0, 75497472, stream);                 // P1 halo + ch 24..31
    hipMemsetAsync(B, 0, 40960000, stream);                 // P2 halo + ch 48..63
    hipLaunchKernelGGL(conv0_kernel, dim3((64 * 6 * 92 * 23 + 255) / 256), dim3(256), 0, stream,
                       XP, F0, b0, A, P1LO);

    // --- conv1 (+pool) : P1 -> P2, two x-halves ---
    hipLaunchKernelGGL((conv_mfma_kernel<32, 3, 3, 1, 52, true, 0>), dim3(64 * 46), dim3(192), 0, stream,
                       A, P1LO, WF1, 38400, b1, B, P2LO, (float*)nullptr,
                       96, 96, 46, 92, 0, 0, 32, 50, 50, 64, 46);
    hipLaunchKernelGGL((conv_mfma_kernel<32, 3, 3, 1, 52, true, 0>), dim3(64 * 46), dim3(192), 0, stream,
                       A, P1LO, WF1, 38400, b1, B, P2LO, (float*)nullptr,
                       96, 96, 46, 92, 44, 46, 76, 50, 50, 64, 46);

    // --- conv2 : P2 -> P3 (A) ---
    hipMemsetAsync(A, 0, 40960000, stream);                 // P3 region
    hipLaunchKernelGGL((conv_mfma_kernel<64, 3, 3, 1, 50, false, 0>), dim3(64 * 46), dim3(192), 0, stream,
                       B, P2LO, WF2, 76800, b2, A, P2LO, (float*)nullptr,
                       50, 50, 46, 46, 0, 0, 30, 50, 50, 64, 46);

    // --- conv3 (+pool) : P3 -> P4 (B), two x-halves ---
    hipMemsetAsync(B, 0, 17915904, stream);                 // P4 region
    hipLaunchKernelGGL((conv_mfma_kernel<64, 6, 2, 2, 36, true, 0>), dim3(64 * 23), dim3(192), 0, stream,
                       A, P2LO, WF3, 153600, b3, B, P4LO, (float*)nullptr,
                       50, 50, 23, 46, 0, 0, 16, 27, 27, 96, 23);
    hipLaunchKernelGGL((conv_mfma_kernel<64, 6, 1, 2, 20, true, 0>), dim3(64 * 23), dim3(192), 0, stream,
                       A, P2LO, WF3, 153600, b3, B, P4LO, (float*)nullptr,
                       50, 50, 23, 46, 30, 30, 30, 27, 27, 96, 23);

    // --- conv4 : P4 -> P5 (A) ---
    hipMemsetAsync(A, 0, 17915904, stream);                 // P5 region
    hipLaunchKernelGGL((conv_mfma_kernel<96, 6, 2, 2, 28, false, 0>), dim3(64 * 23), dim3(192), 0, stream,
                       B, P4LO, WF4, 230400, b4, A, P4LO, (float*)nullptr,
                       27, 27, 23, 23, 0, 0, 7, 27, 27, 96, 23);

    // --- conv5 : P5 -> C5 (fp32 NHWC compact) ---
    hipLaunchKernelGGL((conv_mfma_kernel<96, 4, 2, 1, 28, false, 1>), dim3(64 * 21), dim3(256), 0, stream,
                       A, P4LO, WF5, 153600, b5, (u16*)A /*unused*/, 0, C5,
                       27, 27, 21, 21, 0, 0, 7, 27, 27, 96, 21);

    // --- mean + fc ---
    hipLaunchKernelGGL(mean_nhwc_kernel, dim3(64), dim3(256), 0, stream, C5, MEANB);
    hipLaunchKernelGGL(fc_kernel, dim3(1), dim3(256), 0, stream,
                       MEANB, fw1, fb1, fw2, fb2, (float*)d_out);
}